// Round 7
// baseline (227.944 us; speedup 1.0000x reference)
//
#include <hip/hip_runtime.h>

// ---------------- problem constants ----------------
#define BM   8192      // B*M
#define NN1  16384
#define NN2  8192
#define NN3  4096
#define NB   80        // y bins, width 1.0
#define NBLK 32        // sort chunks
#define ITEMS 65536    // 8192 LR + 2*(16384+8192+4096) HR
#define CHUNK 2048     // ITEMS/NBLK

// ---------------- workspace layout (float element offsets) ----------------
#define OFF_LRS   0            // 8192 float4 y-sorted, w=orig p
#define OFF_S1    32768        // sorted HR1, w=orig j in batch
#define OFF_S2    163840
#define OFF_S3    229376
#define OFF_F1    262144       // 2*16384*32 f32, orig-indexed
#define OFF_F2    1310720
#define OFF_F3    1835008
#define OFF_ACC1  2097152      // 8192*32 f32 FINAL grouped features (fallback folded in)
#define OFF_ACC2  2359296
#define OFF_ACC3  2621440
#define OFF_PART  2883584      // int[32*640]
#define OFF_BASE  2904064      // int[32*640]
#define OFF_START 2924544      // int[648] (pad 1024)
#define OFF_WP    2925568      // 160*64 BN-folded w_out
#define OFF_SHIFT 2935808      // 64
#define WS_FLOATS 2935872      // ~11.7 MB

// table ids: HR s*2+b -> 0..5 ; LR 6+b

// ---------------- kernel A: fused y-histogram + F precompute + folded BN ----------------
// blocks 0..31: per-chunk LDS histogram of all 65536 items.
// blocks 32.. : flat elementwise sections.
__global__ __launch_bounds__(256) void kprep(
    const int* __restrict__ lr_idx, const int* __restrict__ h1i,
    const int* __restrict__ h2i, const int* __restrict__ h3i,
    const float* __restrict__ f1, const float* __restrict__ f2, const float* __restrict__ f3,
    const float* __restrict__ w14, const float* __restrict__ b14,
    const float* __restrict__ w24, const float* __restrict__ b24,
    const float* __restrict__ w34, const float* __restrict__ b34,
    const float* __restrict__ wout, const float* __restrict__ gam,
    const float* __restrict__ bet, const float* __restrict__ mean,
    const float* __restrict__ var, float* __restrict__ ws)
{
    __shared__ int hist[640];
    int bx = blockIdx.x, tid = threadIdx.x;

    if (bx < NBLK) {   // ---- histogram section ----
        for (int e = tid; e < 640; e += 256) hist[e] = 0;
        __syncthreads();
        int base_it = bx * CHUNK;
        for (int t = tid; t < CHUNK; t += 256) {
            int e = base_it + t;
            int T, iy; float vsx;
            if (e < 8192)            { T = 6 + (e>>12); iy = lr_idx[e*3+1]; vsx = 0.4f; }
            else { int r = e - 8192;
              if (r < 32768)         { int b = r>>14; T = b;   iy = h1i[r*3+1]; vsx = 0.05f; }
              else { r -= 32768;
                if (r < 16384)       { int b = r>>13; T = 2+b; iy = h2i[r*3+1]; vsx = 0.1f; }
                else { r -= 16384; int b = r>>12; T = 4+b; iy = h3i[r*3+1]; vsx = 0.2f; }
              }
            }
            float y = __fadd_rn(__fadd_rn(__fmul_rn((float)iy, vsx), -40.0f), __fmul_rn(0.5f, vsx));
            int k = min(NB-1, max(0, (int)floorf(y + 40.0f)));
            atomicAdd(&hist[T*80 + k], 1);
        }
        __syncthreads();
        for (int e = tid; e < 640; e += 256)
            reinterpret_cast<int*>(ws)[OFF_PART + bx*640 + e] = hist[e];
        return;
    }

    int e = (bx - NBLK) * 256 + tid;

    // [0] F1: 4 channels/thread. o2=e&7 -> channels o2*4.., jj=e>>3
    if (e < 262144) {
        int o2 = e & 7, jj = e >> 3;
        const float4* fv = reinterpret_cast<const float4*>(f1) + jj*4;
        const float4* w4 = reinterpret_cast<const float4*>(w14);
        float4 acc = reinterpret_cast<const float4*>(b14)[o2];
        float fr[16];
        #pragma unroll
        for (int c4 = 0; c4 < 4; ++c4) {
            float4 f = fv[c4];
            fr[c4*4] = f.x; fr[c4*4+1] = f.y; fr[c4*4+2] = f.z; fr[c4*4+3] = f.w;
        }
        #pragma unroll
        for (int c = 0; c < 16; ++c) {
            float4 w = w4[(3+c)*8 + o2];
            acc.x = fmaf(fr[c], w.x, acc.x); acc.y = fmaf(fr[c], w.y, acc.y);
            acc.z = fmaf(fr[c], w.z, acc.z); acc.w = fmaf(fr[c], w.w, acc.w);
        }
        reinterpret_cast<float4*>(ws + OFF_F1)[jj*8 + o2] = acc;
        return;
    }
    e -= 262144;
    if (e < 131072) {
        int o2 = e & 7, jj = e >> 3;
        const float4* fv = reinterpret_cast<const float4*>(f2) + jj*8;
        const float4* w4 = reinterpret_cast<const float4*>(w24);
        float4 acc = reinterpret_cast<const float4*>(b24)[o2];
        #pragma unroll
        for (int cc = 0; cc < 32; cc += 16) {
            float fr[16];
            #pragma unroll
            for (int c4 = 0; c4 < 4; ++c4) {
                float4 f = fv[cc/4 + c4];
                fr[c4*4] = f.x; fr[c4*4+1] = f.y; fr[c4*4+2] = f.z; fr[c4*4+3] = f.w;
            }
            #pragma unroll
            for (int c = 0; c < 16; ++c) {
                float4 w = w4[(3+cc+c)*8 + o2];
                acc.x = fmaf(fr[c], w.x, acc.x); acc.y = fmaf(fr[c], w.y, acc.y);
                acc.z = fmaf(fr[c], w.z, acc.z); acc.w = fmaf(fr[c], w.w, acc.w);
            }
        }
        reinterpret_cast<float4*>(ws + OFF_F2)[jj*8 + o2] = acc;
        return;
    }
    e -= 131072;
    if (e < 65536) {
        int o2 = e & 7, jj = e >> 3;
        const float4* fv = reinterpret_cast<const float4*>(f3) + jj*16;
        const float4* w4 = reinterpret_cast<const float4*>(w34);
        float4 acc = reinterpret_cast<const float4*>(b34)[o2];
        #pragma unroll
        for (int cc = 0; cc < 64; cc += 16) {
            float fr[16];
            #pragma unroll
            for (int c4 = 0; c4 < 4; ++c4) {
                float4 f = fv[cc/4 + c4];
                fr[c4*4] = f.x; fr[c4*4+1] = f.y; fr[c4*4+2] = f.z; fr[c4*4+3] = f.w;
            }
            #pragma unroll
            for (int c = 0; c < 16; ++c) {
                float4 w = w4[(3+cc+c)*8 + o2];
                acc.x = fmaf(fr[c], w.x, acc.x); acc.y = fmaf(fr[c], w.y, acc.y);
                acc.z = fmaf(fr[c], w.z, acc.z); acc.w = fmaf(fr[c], w.w, acc.w);
            }
        }
        reinterpret_cast<float4*>(ws + OFF_F3)[jj*8 + o2] = acc;
        return;
    }
    e -= 65536;

    // [3] BN-folded w' and shift (padded to 10496)
    if (e < 10240) {
        int o = e & 63;
        float sc = gam[o] * (1.0f / sqrtf(var[o] + 1e-3f));
        ws[OFF_WP + e] = wout[e] * sc;
    } else if (e < 10304) {
        int o = e - 10240;
        float sc = gam[o] * (1.0f / sqrtf(var[o] + 1e-3f));
        ws[OFF_SHIFT + o] = bet[o] - mean[o] * sc;
    }
}

// ---------------- kernel B: totals, wave-scan prefix, per-block bases ----------------
__global__ __launch_bounds__(1024) void khist2(float* __restrict__ ws)
{
    __shared__ int totS[640];
    __shared__ int stt[648];
    int t = threadIdx.x;
    int* wsi = reinterpret_cast<int*>(ws);
    int part[NBLK];
    if (t < 640) {
        int sm = 0;
        #pragma unroll
        for (int b = 0; b < NBLK; ++b) { part[b] = wsi[OFF_PART + b*640 + t]; sm += part[b]; }
        totS[t] = sm;
    }
    __syncthreads();
    int wid = t >> 6, lane = t & 63;
    if (wid < 8) {
        int v = totS[wid*80 + lane];
        #pragma unroll
        for (int s = 1; s < 64; s <<= 1) { int u = __shfl_up(v, s); if (lane >= s) v += u; }
        int base64 = __shfl(v, 63);
        int v2 = (lane < 16) ? totS[wid*80 + 64 + lane] : 0;
        #pragma unroll
        for (int s = 1; s < 16; s <<= 1) { int u = __shfl_up(v2, s); if (lane >= s) v2 += u; }
        if (lane == 0) stt[wid*81] = 0;
        stt[wid*81 + 1 + lane] = v;
        if (lane < 16) stt[wid*81 + 65 + lane] = base64 + v2;
    }
    __syncthreads();
    if (t < 648) wsi[OFF_START + t] = stt[t];
    if (t < 640) {
        int run = stt[(t/80)*81 + (t%80)];
        #pragma unroll
        for (int b = 0; b < NBLK; ++b) { wsi[OFF_BASE + b*640 + t] = run; run += part[b]; }
    }
}

// ---------------- kernel C: scatter with LDS cursors ----------------
__global__ __launch_bounds__(1024) void kscatter(
    const int* __restrict__ lr_idx, const int* __restrict__ h1i,
    const int* __restrict__ h2i, const int* __restrict__ h3i,
    float* __restrict__ ws)
{
    __shared__ int cur[640];
    int tid = threadIdx.x, bx = blockIdx.x;
    if (tid < 640) cur[tid] = reinterpret_cast<int*>(ws)[OFF_BASE + bx*640 + tid];
    __syncthreads();
    int base_it = bx * CHUNK;
    for (int t = tid; t < CHUNK; t += 1024) {
        int e = base_it + t;
        int T, w, dst4, r3; const int* ip; float vsx, vsz;
        if (e < 8192) {
            int b = e >> 12; T = 6+b; ip = lr_idx; r3 = e*3; vsx = 0.4f; vsz = 1.0f;
            w = e; dst4 = OFF_LRS/4 + b*4096;
        } else { int r = e - 8192;
          if (r < 32768) { int b = r>>14; T = b;   ip = h1i; r3 = r*3; vsx = 0.05f; vsz = 0.1f; w = r - b*NN1; dst4 = OFF_S1/4 + b*NN1; }
          else { r -= 32768;
            if (r < 16384) { int b = r>>13; T = 2+b; ip = h2i; r3 = r*3; vsx = 0.1f; vsz = 0.2f; w = r - b*NN2; dst4 = OFF_S2/4 + b*NN2; }
            else { r -= 16384; int b = r>>12; T = 4+b; ip = h3i; r3 = r*3; vsx = 0.2f; vsz = 0.4f; w = r - b*NN3; dst4 = OFF_S3/4 + b*NN3; }
          }
        }
        int iz = ip[r3], iy = ip[r3+1], ix = ip[r3+2];
        float4 v;
        v.x = __fadd_rn(__fadd_rn(__fmul_rn((float)ix, vsx),   0.0f), __fmul_rn(0.5f, vsx));
        v.y = __fadd_rn(__fadd_rn(__fmul_rn((float)iy, vsx), -40.0f), __fmul_rn(0.5f, vsx));
        v.z = __fadd_rn(__fadd_rn(__fmul_rn((float)iz, vsz),  -3.0f), __fmul_rn(0.5f, vsz));
        v.w = __int_as_float(w);
        int k = min(NB-1, max(0, (int)floorf(v.y + 40.0f)));
        int pos = atomicAdd(&cur[T*80 + k], 1);
        reinterpret_cast<float4*>(ws)[dst4 + pos] = v;
    }
}

// ---------------- kernel D: inverted pruned scan ----------------
// Block = (set, 64-point group). Each wave: ONE coalesced load of 64 candidates,
// then 64-point VALU sweep from LDS. Fallback (cnt==0) resolved in writeback.
__global__ __launch_bounds__(1024) void kscan(
    float* __restrict__ ws,
    const int* __restrict__ h1i, const int* __restrict__ h2i, const int* __restrict__ h3i,
    const float* __restrict__ w14, const float* __restrict__ w24, const float* __restrict__ w34)
{
    __shared__ int   accS[64*33];   // stride 33: conflict-free
    __shared__ float lrS[64*4];
    __shared__ float wSS[96];
    __shared__ float F0S[32];
    __shared__ int   cntS[64];
    __shared__ int   porigS[64];

    int bx = blockIdx.x;
    int s = bx >> 7, pg = bx & 127;
    const float* wS; const int* hidx; int soff, Foff, accoff, N; float vsx, vsz;
    if (s == 0)      { wS=w14; hidx=h1i; soff=OFF_S1; Foff=OFF_F1; accoff=OFF_ACC1; N=NN1; vsx=0.05f; vsz=0.1f; }
    else if (s == 1) { wS=w24; hidx=h2i; soff=OFF_S2; Foff=OFF_F2; accoff=OFF_ACC2; N=NN2; vsx=0.1f;  vsz=0.2f; }
    else             { wS=w34; hidx=h3i; soff=OFF_S3; Foff=OFF_F3; accoff=OFF_ACC3; N=NN3; vsx=0.2f;  vsz=0.4f; }

    int tid = threadIdx.x, lane = tid & 63, wv = tid >> 6;
    int b = pg >> 6;

    for (int e = tid; e < 64*33; e += 1024) accS[e] = 0;
    if (tid < 96) wSS[tid] = wS[tid];
    if (tid < 64) {
        float4 l = reinterpret_cast<const float4*>(ws + OFF_LRS)[pg*64 + tid];
        reinterpret_cast<float4*>(lrS)[tid] = l;
        porigS[tid] = __float_as_int(l.w);
        cntS[tid] = 0;
    }
    if (tid < 32) F0S[tid] = ws[Foff + (size_t)b*N*32 + tid];

    float4 lr = reinterpret_cast<const float4*>(ws + OFF_LRS)[pg*64 + lane];
    float ymin = lr.y, ymax = lr.y;
    #pragma unroll
    for (int m = 1; m < 64; m <<= 1) {
        ymin = fminf(ymin, __shfl_xor(ymin, m));
        ymax = fmaxf(ymax, __shfl_xor(ymax, m));
    }
    int klo = max(0, (int)floorf(ymin - 1.001f + 40.0f));
    int khi = min(NB-1, (int)floorf(ymax + 1.001f + 40.0f));
    const int* st = reinterpret_cast<const int*>(ws) + OFF_START + (s*2+b)*81;
    int j0 = st[klo], j1 = st[khi+1];
    int len = j1 - j0;
    int ja_w = j0 + (len * wv) / 16;
    int je_w = j0 + (len * (wv+1)) / 16;

    const float4* S = reinterpret_cast<const float4*>(ws + soff) + b*N;
    const float* Fb = ws + Foff + (size_t)b*N*32;

    __syncthreads();

    for (int jb = ja_w; jb < je_w; jb += 64) {
        int j = jb + lane;
        bool valid = (j < je_w);
        float4 q;
        if (valid) q = S[j]; else { q.x = 1e30f; q.y = 1e30f; q.z = 1e30f; q.w = 0.f; }
        const float* Fr = Fb + (size_t)__float_as_int(q.w) * 32;
        #pragma unroll 2
        for (int p = 0; p < 64; ++p) {
            float4 l = reinterpret_cast<const float4*>(lrS)[p];   // LDS broadcast
            float dx = q.x - l.x, dy = q.y - l.y, dz = q.z - l.z;
            float d2 = __fadd_rn(__fadd_rn(__fmul_rn(dx,dx), __fmul_rn(dy,dy)), __fmul_rn(dz,dz));
            if (d2 < 1.0f) {
                cntS[p] = 1;                       // benign same-value race
                int* accP = accS + p*33;
                #pragma unroll
                for (int o4 = 0; o4 < 8; ++o4) {
                    float4 f4  = reinterpret_cast<const float4*>(Fr)[o4];
                    float4 wx4 = reinterpret_cast<const float4*>(wSS)[o4];
                    float4 wy4 = reinterpret_cast<const float4*>(wSS + 32)[o4];
                    float4 wz4 = reinterpret_cast<const float4*>(wSS + 64)[o4];
                    atomicMax(accP + o4*4+0, __float_as_int(f4.x + dx*wx4.x + dy*wy4.x + dz*wz4.x));
                    atomicMax(accP + o4*4+1, __float_as_int(f4.y + dx*wx4.y + dy*wy4.y + dz*wz4.y));
                    atomicMax(accP + o4*4+2, __float_as_int(f4.z + dx*wx4.z + dy*wy4.z + dz*wz4.z));
                    atomicMax(accP + o4*4+3, __float_as_int(f4.w + dx*wx4.w + dy*wy4.w + dz*wz4.w));
                }
            }
        }
    }
    __syncthreads();

    // fallback coords: original j=0 of this (set,batch)
    int i0 = b * N * 3;
    int hz = hidx[i0], hy = hidx[i0+1], hx = hidx[i0+2];
    float q0x = __fadd_rn(__fadd_rn(__fmul_rn((float)hx, vsx),   0.0f), __fmul_rn(0.5f, vsx));
    float q0y = __fadd_rn(__fadd_rn(__fmul_rn((float)hy, vsx), -40.0f), __fmul_rn(0.5f, vsx));
    float q0z = __fadd_rn(__fadd_rn(__fmul_rn((float)hz, vsz),  -3.0f), __fmul_rn(0.5f, vsz));

    float* accG = ws + accoff;
    for (int e = tid; e < 2048; e += 1024) {
        int i = e >> 5, o = e & 31;
        float v;
        if (cntS[i]) v = __int_as_float(accS[i*33 + o]);
        else {
            float dx = q0x - lrS[i*4], dy = q0y - lrS[i*4+1], dz = q0z - lrS[i*4+2];
            v = fmaxf(F0S[o] + dx*wSS[o] + dy*wSS[32+o] + dz*wSS[64+o], 0.f);
        }
        accG[porigS[i]*32 + o] = v;
    }
}

// ---------------- kernel E: concat + 160x64 matmul + BN + ReLU ----------------
__global__ __launch_bounds__(256) void kfinal(
    const float* __restrict__ ws, const float* __restrict__ lr_feat, float* __restrict__ out)
{
    __shared__ float cat_s[32][160];
    int tid = threadIdx.x;
    int p0 = blockIdx.x * 32;

    const float4* lrf4 = reinterpret_cast<const float4*>(lr_feat + p0*64);
    #pragma unroll
    for (int r = 0; r < 2; ++r) {
        int e = tid + r*256;                 // [0,512): pt=e>>4, c4=e&15
        float4 v = lrf4[e];
        *reinterpret_cast<float4*>(&cat_s[e>>4][(e&15)*4]) = v;
    }
    {
        const float4* a1 = reinterpret_cast<const float4*>(ws + OFF_ACC1 + p0*32);
        const float4* a2 = reinterpret_cast<const float4*>(ws + OFF_ACC2 + p0*32);
        const float4* a3 = reinterpret_cast<const float4*>(ws + OFF_ACC3 + p0*32);
        int pt = tid >> 3, o4 = tid & 7;     // [0,256)
        float4 v1 = a1[tid]; *reinterpret_cast<float4*>(&cat_s[pt][64 + o4*4]) = v1;
        float4 v2 = a2[tid]; *reinterpret_cast<float4*>(&cat_s[pt][96 + o4*4]) = v2;
        float4 v3 = a3[tid]; *reinterpret_cast<float4*>(&cat_s[pt][128 + o4*4]) = v3;
    }
    __syncthreads();

    int wv = tid >> 6, lane = tid & 63;
    float sh = ws[OFF_SHIFT + lane];
    float acc[8];
    #pragma unroll
    for (int pt = 0; pt < 8; ++pt) acc[pt] = sh;

    const float* wp = ws + OFF_WP;
    #pragma unroll 2
    for (int c = 0; c < 160; c += 4) {
        float w0 = wp[(c+0)*64 + lane];
        float w1 = wp[(c+1)*64 + lane];
        float w2 = wp[(c+2)*64 + lane];
        float w3 = wp[(c+3)*64 + lane];
        #pragma unroll
        for (int pt = 0; pt < 8; ++pt) {
            float4 cv = *reinterpret_cast<const float4*>(&cat_s[wv*8 + pt][c]);
            acc[pt] = fmaf(cv.x, w0, acc[pt]);
            acc[pt] = fmaf(cv.y, w1, acc[pt]);
            acc[pt] = fmaf(cv.z, w2, acc[pt]);
            acc[pt] = fmaf(cv.w, w3, acc[pt]);
        }
    }
    #pragma unroll
    for (int pt = 0; pt < 8; ++pt)
        out[(p0 + wv*8 + pt) * 64 + lane] = fmaxf(acc[pt], 0.f);
}

// ---------------- host launcher ----------------
extern "C" void kernel_launch(void* const* d_in, const int* in_sizes, int n_in,
                              void* d_out, int out_size, void* d_ws, size_t ws_size,
                              hipStream_t stream) {
    const int*   lr_idx = (const int*)d_in[0];
    const int*   h1i    = (const int*)d_in[1];
    const int*   h2i    = (const int*)d_in[2];
    const int*   h3i    = (const int*)d_in[3];
    const float* lrf    = (const float*)d_in[4];
    const float* f1     = (const float*)d_in[5];
    const float* f2     = (const float*)d_in[6];
    const float* f3     = (const float*)d_in[7];
    const float* w14    = (const float*)d_in[8];
    const float* b14    = (const float*)d_in[9];
    const float* w24    = (const float*)d_in[10];
    const float* b24    = (const float*)d_in[11];
    const float* w34    = (const float*)d_in[12];
    const float* b34    = (const float*)d_in[13];
    const float* wout   = (const float*)d_in[14];
    const float* gam    = (const float*)d_in[15];
    const float* bet    = (const float*)d_in[16];
    const float* mean   = (const float*)d_in[17];
    const float* var    = (const float*)d_in[18];
    float* ws  = (float*)d_ws;
    float* out = (float*)d_out;

    if (ws_size < (size_t)WS_FLOATS * sizeof(float)) return;  // ~11.7 MB scratch

    // A: 32 hist blocks + (262144+131072+65536+10496)/256 = 1833 flat blocks
    kprep<<<1865, 256, 0, stream>>>(lr_idx, h1i, h2i, h3i, f1, f2, f3,
                                    w14, b14, w24, b24, w34, b34,
                                    wout, gam, bet, mean, var, ws);
    khist2<<<1, 1024, 0, stream>>>(ws);
    kscatter<<<NBLK, 1024, 0, stream>>>(lr_idx, h1i, h2i, h3i, ws);
    // 384 blocks = 3 sets x 128 point-groups, 16 waves each
    kscan<<<384, 1024, 0, stream>>>(ws, h1i, h2i, h3i, w14, w24, w34);
    kfinal<<<256, 256, 0, stream>>>(ws, lrf, out);
}

// Round 8
// 143.317 us; speedup vs baseline: 1.5905x; 1.5905x over previous
//
#include <hip/hip_runtime.h>

// ---------------- problem constants ----------------
#define BM   8192      // B*M
#define NN1  16384
#define NN2  8192
#define NN3  4096
#define NB   80        // y bins, width 1.0
#define NBLK 32        // sort chunks
#define ITEMS 65536    // 8192 LR + 2*(16384+8192+4096) HR
#define CHUNK 2048     // ITEMS/NBLK
#define TSZ  1280      // staged candidates per tile (20 KB)
#define QCAP 1024      // hit queue capacity (avg ~192 hits/block, >50 sigma margin)

// ---------------- workspace layout (float element offsets) ----------------
#define OFF_LRS   0            // 8192 float4 y-sorted, w=orig p
#define OFF_S1    32768        // sorted HR1, w=orig j in batch
#define OFF_S2    163840
#define OFF_S3    229376
#define OFF_F1    262144       // 2*16384*32 f32, orig-indexed
#define OFF_F2    1310720
#define OFF_F3    1835008
#define OFF_ACC1  2097152      // 8192*32 f32 FINAL grouped features (fallback folded)
#define OFF_ACC2  2359296
#define OFF_ACC3  2621440
#define OFF_PART  2883584      // int[32*640]
#define OFF_START 2924544      // int[648] (pad 1024)
#define OFF_WP    2925568      // 160*64 BN-folded w_out
#define OFF_SHIFT 2935808      // 64
#define WS_FLOATS 2935872      // ~11.7 MB

// table ids: HR s*2+b -> 0..5 ; LR 6+b

// ---------------- kernel A: fused y-histogram + F precompute + folded BN ----------------
__global__ __launch_bounds__(256) void kprep(
    const int* __restrict__ lr_idx, const int* __restrict__ h1i,
    const int* __restrict__ h2i, const int* __restrict__ h3i,
    const float* __restrict__ f1, const float* __restrict__ f2, const float* __restrict__ f3,
    const float* __restrict__ w14, const float* __restrict__ b14,
    const float* __restrict__ w24, const float* __restrict__ b24,
    const float* __restrict__ w34, const float* __restrict__ b34,
    const float* __restrict__ wout, const float* __restrict__ gam,
    const float* __restrict__ bet, const float* __restrict__ mean,
    const float* __restrict__ var, float* __restrict__ ws)
{
    __shared__ int hist[640];
    int bx = blockIdx.x, tid = threadIdx.x;

    if (bx < NBLK) {   // ---- histogram section ----
        for (int e = tid; e < 640; e += 256) hist[e] = 0;
        __syncthreads();
        int base_it = bx * CHUNK;
        for (int t = tid; t < CHUNK; t += 256) {
            int e = base_it + t;
            int T, iy; float vsx;
            if (e < 8192)            { T = 6 + (e>>12); iy = lr_idx[e*3+1]; vsx = 0.4f; }
            else { int r = e - 8192;
              if (r < 32768)         { int b = r>>14; T = b;   iy = h1i[r*3+1]; vsx = 0.05f; }
              else { r -= 32768;
                if (r < 16384)       { int b = r>>13; T = 2+b; iy = h2i[r*3+1]; vsx = 0.1f; }
                else { r -= 16384; int b = r>>12; T = 4+b; iy = h3i[r*3+1]; vsx = 0.2f; }
              }
            }
            float y = __fadd_rn(__fadd_rn(__fmul_rn((float)iy, vsx), -40.0f), __fmul_rn(0.5f, vsx));
            int k = min(NB-1, max(0, (int)floorf(y + 40.0f)));
            atomicAdd(&hist[T*80 + k], 1);
        }
        __syncthreads();
        for (int e = tid; e < 640; e += 256)
            reinterpret_cast<int*>(ws)[OFF_PART + bx*640 + e] = hist[e];
        return;
    }

    int e = (bx - NBLK) * 256 + tid;

    // [0] F1: 4 channels/thread
    if (e < 262144) {
        int o2 = e & 7, jj = e >> 3;
        const float4* fv = reinterpret_cast<const float4*>(f1) + jj*4;
        const float4* w4 = reinterpret_cast<const float4*>(w14);
        float4 acc = reinterpret_cast<const float4*>(b14)[o2];
        float fr[16];
        #pragma unroll
        for (int c4 = 0; c4 < 4; ++c4) {
            float4 f = fv[c4];
            fr[c4*4] = f.x; fr[c4*4+1] = f.y; fr[c4*4+2] = f.z; fr[c4*4+3] = f.w;
        }
        #pragma unroll
        for (int c = 0; c < 16; ++c) {
            float4 w = w4[(3+c)*8 + o2];
            acc.x = fmaf(fr[c], w.x, acc.x); acc.y = fmaf(fr[c], w.y, acc.y);
            acc.z = fmaf(fr[c], w.z, acc.z); acc.w = fmaf(fr[c], w.w, acc.w);
        }
        reinterpret_cast<float4*>(ws + OFF_F1)[jj*8 + o2] = acc;
        return;
    }
    e -= 262144;
    if (e < 131072) {
        int o2 = e & 7, jj = e >> 3;
        const float4* fv = reinterpret_cast<const float4*>(f2) + jj*8;
        const float4* w4 = reinterpret_cast<const float4*>(w24);
        float4 acc = reinterpret_cast<const float4*>(b24)[o2];
        #pragma unroll
        for (int cc = 0; cc < 32; cc += 16) {
            float fr[16];
            #pragma unroll
            for (int c4 = 0; c4 < 4; ++c4) {
                float4 f = fv[cc/4 + c4];
                fr[c4*4] = f.x; fr[c4*4+1] = f.y; fr[c4*4+2] = f.z; fr[c4*4+3] = f.w;
            }
            #pragma unroll
            for (int c = 0; c < 16; ++c) {
                float4 w = w4[(3+cc+c)*8 + o2];
                acc.x = fmaf(fr[c], w.x, acc.x); acc.y = fmaf(fr[c], w.y, acc.y);
                acc.z = fmaf(fr[c], w.z, acc.z); acc.w = fmaf(fr[c], w.w, acc.w);
            }
        }
        reinterpret_cast<float4*>(ws + OFF_F2)[jj*8 + o2] = acc;
        return;
    }
    e -= 131072;
    if (e < 65536) {
        int o2 = e & 7, jj = e >> 3;
        const float4* fv = reinterpret_cast<const float4*>(f3) + jj*16;
        const float4* w4 = reinterpret_cast<const float4*>(w34);
        float4 acc = reinterpret_cast<const float4*>(b34)[o2];
        #pragma unroll
        for (int cc = 0; cc < 64; cc += 16) {
            float fr[16];
            #pragma unroll
            for (int c4 = 0; c4 < 4; ++c4) {
                float4 f = fv[cc/4 + c4];
                fr[c4*4] = f.x; fr[c4*4+1] = f.y; fr[c4*4+2] = f.z; fr[c4*4+3] = f.w;
            }
            #pragma unroll
            for (int c = 0; c < 16; ++c) {
                float4 w = w4[(3+cc+c)*8 + o2];
                acc.x = fmaf(fr[c], w.x, acc.x); acc.y = fmaf(fr[c], w.y, acc.y);
                acc.z = fmaf(fr[c], w.z, acc.z); acc.w = fmaf(fr[c], w.w, acc.w);
            }
        }
        reinterpret_cast<float4*>(ws + OFF_F3)[jj*8 + o2] = acc;
        return;
    }
    e -= 65536;

    // [3] BN-folded w' and shift
    if (e < 10240) {
        int o = e & 63;
        float sc = gam[o] * (1.0f / sqrtf(var[o] + 1e-3f));
        ws[OFF_WP + e] = wout[e] * sc;
    } else if (e < 10304) {
        int o = e - 10240;
        float sc = gam[o] * (1.0f / sqrtf(var[o] + 1e-3f));
        ws[OFF_SHIFT + o] = bet[o] - mean[o] * sc;
    }
}

// ---------------- kernel B: fused prefix + scatter (each block derives cursors) ----------------
__global__ __launch_bounds__(1024) void kscatter(
    const int* __restrict__ lr_idx, const int* __restrict__ h1i,
    const int* __restrict__ h2i, const int* __restrict__ h3i,
    float* __restrict__ ws)
{
    __shared__ int totS[640];
    __shared__ int stt[648];
    __shared__ int cur[640];
    int t = threadIdx.x, bx = blockIdx.x;
    int* wsi = reinterpret_cast<int*>(ws);

    int tot = 0, mypre = 0;
    if (t < 640) {
        #pragma unroll
        for (int b = 0; b < NBLK; ++b) {
            int p = wsi[OFF_PART + b*640 + t];
            tot += p;
            if (b < bx) mypre += p;
        }
        totS[t] = tot;
    }
    __syncthreads();
    int wid = t >> 6, lane = t & 63;
    if (wid < 8) {
        int v = totS[wid*80 + lane];
        #pragma unroll
        for (int s = 1; s < 64; s <<= 1) { int u = __shfl_up(v, s); if (lane >= s) v += u; }
        int base64 = __shfl(v, 63);
        int v2 = (lane < 16) ? totS[wid*80 + 64 + lane] : 0;
        #pragma unroll
        for (int s = 1; s < 16; s <<= 1) { int u = __shfl_up(v2, s); if (lane >= s) v2 += u; }
        if (lane == 0) stt[wid*81] = 0;
        stt[wid*81 + 1 + lane] = v;
        if (lane < 16) stt[wid*81 + 65 + lane] = base64 + v2;
    }
    __syncthreads();
    if (bx == 0 && t < 648) wsi[OFF_START + t] = stt[t];
    if (t < 640) cur[t] = stt[(t/80)*81 + (t%80)] + mypre;
    __syncthreads();

    int base_it = bx * CHUNK;
    for (int tt = t; tt < CHUNK; tt += 1024) {
        int e = base_it + tt;
        int T, w, dst4, r3; const int* ip; float vsx, vsz;
        if (e < 8192) {
            int b = e >> 12; T = 6+b; ip = lr_idx; r3 = e*3; vsx = 0.4f; vsz = 1.0f;
            w = e; dst4 = OFF_LRS/4 + b*4096;
        } else { int r = e - 8192;
          if (r < 32768) { int b = r>>14; T = b;   ip = h1i; r3 = r*3; vsx = 0.05f; vsz = 0.1f; w = r - b*NN1; dst4 = OFF_S1/4 + b*NN1; }
          else { r -= 32768;
            if (r < 16384) { int b = r>>13; T = 2+b; ip = h2i; r3 = r*3; vsx = 0.1f; vsz = 0.2f; w = r - b*NN2; dst4 = OFF_S2/4 + b*NN2; }
            else { r -= 16384; int b = r>>12; T = 4+b; ip = h3i; r3 = r*3; vsx = 0.2f; vsz = 0.4f; w = r - b*NN3; dst4 = OFF_S3/4 + b*NN3; }
          }
        }
        int iz = ip[r3], iy = ip[r3+1], ix = ip[r3+2];
        float4 v;
        v.x = __fadd_rn(__fadd_rn(__fmul_rn((float)ix, vsx),   0.0f), __fmul_rn(0.5f, vsx));
        v.y = __fadd_rn(__fadd_rn(__fmul_rn((float)iy, vsx), -40.0f), __fmul_rn(0.5f, vsx));
        v.z = __fadd_rn(__fadd_rn(__fmul_rn((float)iz, vsz),  -3.0f), __fmul_rn(0.5f, vsz));
        v.w = __int_as_float(w);
        int k = min(NB-1, max(0, (int)floorf(v.y + 40.0f)));
        int pos = atomicAdd(&cur[T*80 + k], 1);
        reinterpret_cast<float4*>(ws)[dst4 + pos] = v;
    }
}

// ---------------- kernel C: staged scan + hit compaction + wave-wide MLP ----------------
// Block (512 thr, 8 waves) = (set, 64-point group). Phase 1: candidates staged in
// LDS, lane-owns-point broadcast test, hits pushed as (j<<6|lane) tokens.
// Phase 2: tokens processed one (entry,channel) per lane: coalesced F loads,
// conflict-free LDS atomicMax. Fallback folded into writeback.
__global__ __launch_bounds__(512) void kscan(
    float* __restrict__ ws,
    const int* __restrict__ h1i, const int* __restrict__ h2i, const int* __restrict__ h3i,
    const float* __restrict__ w14, const float* __restrict__ w24, const float* __restrict__ w34)
{
    __shared__ float4 Sst[TSZ];
    __shared__ int   accS[64*33];
    __shared__ float lrS[64*4];
    __shared__ float wSS[96];
    __shared__ float F0S[32];
    __shared__ int   cntS[64];
    __shared__ int   porigS[64];
    __shared__ int   queue[QCAP];
    __shared__ int   qn;

    int bx = blockIdx.x;
    int s = bx >> 7, pg = bx & 127;
    const float* wS; const int* hidx; int soff, Foff, accoff, N; float vsx, vsz;
    if (s == 0)      { wS=w14; hidx=h1i; soff=OFF_S1; Foff=OFF_F1; accoff=OFF_ACC1; N=NN1; vsx=0.05f; vsz=0.1f; }
    else if (s == 1) { wS=w24; hidx=h2i; soff=OFF_S2; Foff=OFF_F2; accoff=OFF_ACC2; N=NN2; vsx=0.1f;  vsz=0.2f; }
    else             { wS=w34; hidx=h3i; soff=OFF_S3; Foff=OFF_F3; accoff=OFF_ACC3; N=NN3; vsx=0.2f;  vsz=0.4f; }

    int tid = threadIdx.x, lane = tid & 63, wv = tid >> 6;   // 8 waves
    int b = pg >> 6;

    for (int e = tid; e < 64*33; e += 512) accS[e] = 0;
    if (tid < 96) wSS[tid] = wS[tid];
    if (tid < 64) {
        float4 l = reinterpret_cast<const float4*>(ws + OFF_LRS)[pg*64 + tid];
        reinterpret_cast<float4*>(lrS)[tid] = l;
        porigS[tid] = __float_as_int(l.w);
        cntS[tid] = 0;
    }
    if (tid < 32) F0S[tid] = ws[Foff + (size_t)b*N*32 + tid];
    if (tid == 0) qn = 0;

    float4 lr = reinterpret_cast<const float4*>(ws + OFF_LRS)[pg*64 + lane];
    float ymin = lr.y, ymax = lr.y;
    #pragma unroll
    for (int m = 1; m < 64; m <<= 1) {
        ymin = fminf(ymin, __shfl_xor(ymin, m));
        ymax = fmaxf(ymax, __shfl_xor(ymax, m));
    }
    int klo = max(0, (int)floorf(ymin - 1.001f + 40.0f));
    int khi = min(NB-1, (int)floorf(ymax + 1.001f + 40.0f));
    const int* st = reinterpret_cast<const int*>(ws) + OFF_START + (s*2+b)*81;
    int j0 = st[klo], j1 = st[khi+1];

    const float4* S = reinterpret_cast<const float4*>(ws + soff) + b*N;
    const float* Fb = ws + Foff + (size_t)b*N*32;

    __syncthreads();

    for (int t0 = j0; t0 < j1; t0 += TSZ) {
        int tlen = min(TSZ, j1 - t0);
        for (int e = tid; e < tlen; e += 512) Sst[e] = S[t0 + e];
        __syncthreads();

        // phase 1: wave wv scans its contiguous share; lane tests its point
        int a   = (tlen * wv) >> 3;
        int bnd = (tlen * (wv+1)) >> 3;
        #pragma unroll 4
        for (int j = a; j < bnd; ++j) {
            float4 q = Sst[j];                       // LDS broadcast
            float dx = q.x - lr.x, dy = q.y - lr.y, dz = q.z - lr.z;
            float d2 = __fadd_rn(__fadd_rn(__fmul_rn(dx,dx), __fmul_rn(dy,dy)), __fmul_rn(dz,dz));
            if (d2 < 1.0f) {                         // exact np op order
                cntS[lane] = 1;                      // benign race
                int pos = atomicAdd(&qn, 1);
                if (pos < QCAP) queue[pos] = (j << 6) | lane;
            }
        }
        __syncthreads();

        // phase 2: wave-wide hit processing (lane = entry x channel)
        int nh = min(qn, QCAP);
        for (int e = tid; e < nh*32; e += 512) {
            int ent = queue[e >> 5], o = e & 31;
            int jl = ent >> 6, p = ent & 63;
            float4 q = Sst[jl];
            float dx = q.x - lrS[p*4], dy = q.y - lrS[p*4+1], dz = q.z - lrS[p*4+2];
            int jo = __float_as_int(q.w);
            float h = Fb[(size_t)jo*32 + o] + dx*wSS[o] + dy*wSS[32+o] + dz*wSS[64+o];
            atomicMax(&accS[p*33 + o], __float_as_int(h));   // 2 lanes/bank: free
        }
        __syncthreads();
        if (tid == 0) qn = 0;   // visible after next stage's barrier
    }

    // writeback with fallback (orig j=0 of this set/batch)
    int i0 = b * N * 3;
    int hz = hidx[i0], hy = hidx[i0+1], hx = hidx[i0+2];
    float q0x = __fadd_rn(__fadd_rn(__fmul_rn((float)hx, vsx),   0.0f), __fmul_rn(0.5f, vsx));
    float q0y = __fadd_rn(__fadd_rn(__fmul_rn((float)hy, vsx), -40.0f), __fmul_rn(0.5f, vsx));
    float q0z = __fadd_rn(__fadd_rn(__fmul_rn((float)hz, vsz),  -3.0f), __fmul_rn(0.5f, vsz));

    __syncthreads();
    float* accG = ws + accoff;
    for (int e = tid; e < 2048; e += 512) {
        int i = e >> 5, o = e & 31;
        float v;
        if (cntS[i]) v = __int_as_float(accS[i*33 + o]);
        else {
            float dx = q0x - lrS[i*4], dy = q0y - lrS[i*4+1], dz = q0z - lrS[i*4+2];
            v = fmaxf(F0S[o] + dx*wSS[o] + dy*wSS[32+o] + dz*wSS[64+o], 0.f);
        }
        accG[porigS[i]*32 + o] = v;
    }
}

// ---------------- kernel D: concat + 160x64 matmul + BN + ReLU ----------------
__global__ __launch_bounds__(256) void kfinal(
    const float* __restrict__ ws, const float* __restrict__ lr_feat, float* __restrict__ out)
{
    __shared__ float cat_s[32][160];
    int tid = threadIdx.x;
    int p0 = blockIdx.x * 32;

    const float4* lrf4 = reinterpret_cast<const float4*>(lr_feat + p0*64);
    #pragma unroll
    for (int r = 0; r < 2; ++r) {
        int e = tid + r*256;
        float4 v = lrf4[e];
        *reinterpret_cast<float4*>(&cat_s[e>>4][(e&15)*4]) = v;
    }
    {
        const float4* a1 = reinterpret_cast<const float4*>(ws + OFF_ACC1 + p0*32);
        const float4* a2 = reinterpret_cast<const float4*>(ws + OFF_ACC2 + p0*32);
        const float4* a3 = reinterpret_cast<const float4*>(ws + OFF_ACC3 + p0*32);
        int pt = tid >> 3, o4 = tid & 7;
        float4 v1 = a1[tid]; *reinterpret_cast<float4*>(&cat_s[pt][64 + o4*4]) = v1;
        float4 v2 = a2[tid]; *reinterpret_cast<float4*>(&cat_s[pt][96 + o4*4]) = v2;
        float4 v3 = a3[tid]; *reinterpret_cast<float4*>(&cat_s[pt][128 + o4*4]) = v3;
    }
    __syncthreads();

    int wv = tid >> 6, lane = tid & 63;
    float sh = ws[OFF_SHIFT + lane];
    float acc[8];
    #pragma unroll
    for (int pt = 0; pt < 8; ++pt) acc[pt] = sh;

    const float* wp = ws + OFF_WP;
    #pragma unroll 2
    for (int c = 0; c < 160; c += 4) {
        float w0 = wp[(c+0)*64 + lane];
        float w1 = wp[(c+1)*64 + lane];
        float w2 = wp[(c+2)*64 + lane];
        float w3 = wp[(c+3)*64 + lane];
        #pragma unroll
        for (int pt = 0; pt < 8; ++pt) {
            float4 cv = *reinterpret_cast<const float4*>(&cat_s[wv*8 + pt][c]);
            acc[pt] = fmaf(cv.x, w0, acc[pt]);
            acc[pt] = fmaf(cv.y, w1, acc[pt]);
            acc[pt] = fmaf(cv.z, w2, acc[pt]);
            acc[pt] = fmaf(cv.w, w3, acc[pt]);
        }
    }
    #pragma unroll
    for (int pt = 0; pt < 8; ++pt)
        out[(p0 + wv*8 + pt) * 64 + lane] = fmaxf(acc[pt], 0.f);
}

// ---------------- host launcher ----------------
extern "C" void kernel_launch(void* const* d_in, const int* in_sizes, int n_in,
                              void* d_out, int out_size, void* d_ws, size_t ws_size,
                              hipStream_t stream) {
    const int*   lr_idx = (const int*)d_in[0];
    const int*   h1i    = (const int*)d_in[1];
    const int*   h2i    = (const int*)d_in[2];
    const int*   h3i    = (const int*)d_in[3];
    const float* lrf    = (const float*)d_in[4];
    const float* f1     = (const float*)d_in[5];
    const float* f2     = (const float*)d_in[6];
    const float* f3     = (const float*)d_in[7];
    const float* w14    = (const float*)d_in[8];
    const float* b14    = (const float*)d_in[9];
    const float* w24    = (const float*)d_in[10];
    const float* b24    = (const float*)d_in[11];
    const float* w34    = (const float*)d_in[12];
    const float* b34    = (const float*)d_in[13];
    const float* wout   = (const float*)d_in[14];
    const float* gam    = (const float*)d_in[15];
    const float* bet    = (const float*)d_in[16];
    const float* mean   = (const float*)d_in[17];
    const float* var    = (const float*)d_in[18];
    float* ws  = (float*)d_ws;
    float* out = (float*)d_out;

    if (ws_size < (size_t)WS_FLOATS * sizeof(float)) return;  // ~11.7 MB scratch

    kprep<<<1865, 256, 0, stream>>>(lr_idx, h1i, h2i, h3i, f1, f2, f3,
                                    w14, b14, w24, b24, w34, b34,
                                    wout, gam, bet, mean, var, ws);
    kscatter<<<NBLK, 1024, 0, stream>>>(lr_idx, h1i, h2i, h3i, ws);
    kscan<<<384, 512, 0, stream>>>(ws, h1i, h2i, h3i, w14, w24, w34);
    kfinal<<<256, 256, 0, stream>>>(ws, lrf, out);
}